// Round 3
// baseline (209.897 us; speedup 1.0000x reference)
//
#include <hip/hip_runtime.h>
#include <cfloat>
#include <cmath>

#define N_NODES 20000
#define MAXD 32
#define F 128

// ---------------- stage 1: trimmed-mean aggregation ----------------

// Batcher odd-even mergesort network, ascending, fully unrolled.
template <int SZ>
__device__ __forceinline__ void oe_sort(float (&a)[SZ]) {
#pragma unroll
  for (int p = 1; p < SZ; p <<= 1) {
#pragma unroll
    for (int q = p; q >= 1; q >>= 1) {
#pragma unroll
      for (int j = q % p; j <= SZ - 1 - q; j += 2 * q) {
#pragma unroll
        for (int i = 0; i < q; ++i) {
          int x = i + j, y = i + j + q;
          if (y < SZ && (x / (2 * p)) == (y / (2 * p))) {
            float mn = fminf(a[x], a[y]);
            float mx = fmaxf(a[x], a[y]);
            a[x] = mn;
            a[y] = mx;
          }
        }
      }
    }
  }
}

// extract element at (block-uniform) position p from a statically-indexed register array
template <int SZ>
__device__ __forceinline__ float extract_pos(const float (&k)[SZ], int p) {
  float sel[SZ];
#pragma unroll
  for (int i = 0; i < SZ; ++i) sel[i] = k[i];
#pragma unroll
  for (int w = SZ >> 1; w >= 1; w >>= 1) {
    bool take = (p & w) != 0;  // p is block-uniform -> scalar branch/select
#pragma unroll
    for (int i = 0; i < w; ++i) sel[i] = take ? sel[i + w] : sel[i];
  }
  return sel[0];
}

// Exact trimmed sum; keys staged in LDS (thread-private column, volatile to pin
// LDS residency so the compiler neither re-gathers from global nor spills).
template <int SZ>
__device__ __forceinline__ float trimmed_sum(const float* __restrict__ h,
                                             const float* __restrict__ norm,
                                             const int* __restrict__ nbr_row,
                                             volatile float* ksf,  // = &ks[f], stride F
                                             int n, int f, int b) {
  float nrm[SZ];  // block-uniform values -> SGPRs
#pragma unroll
  for (int d = 0; d < SZ; ++d) {
    float kv = FLT_MAX, nv = 0.f;  // pads sort past all valid keys
    if (d < n) {                   // uniform branch (n block-uniform)
      int src = nbr_row[d];        // scalar load
      nv = norm[src];              // scalar load
      kv = h[src * F + f];         // vector load, coalesced
    }
    nrm[d] = nv;
    ksf[d * F] = kv;               // LDS write, stride-1 across lanes
  }

  float k[SZ];
#pragma unroll
  for (int d = 0; d < SZ; ++d) k[d] = ksf[d * F];
  oe_sort<SZ>(k);

  const float lo  = extract_pos<SZ>(k, b);          // rank b (kept)
  const float hi  = extract_pos<SZ>(k, n - b - 1);  // rank n-b-1 (kept)
  const float lom = extract_pos<SZ>(k, b - 1);      // rank b-1 (trimmed)
  const float him = extract_pos<SZ>(k, n - b);      // rank n-b (trimmed)

  float sum = 0.f;
  if ((lom < lo) & (hi < him)) {
    // no equal-key run straddles either boundary -> pure value test (exact).
#pragma unroll
    for (int d = 0; d < SZ; ++d) {
      float ko = ksf[d * F];
      bool keep = (ko >= lo) & (ko <= hi);  // pads (FLT_MAX) fail, and nrm=0 anyway
      sum = fmaf(keep ? ko : 0.f, nrm[d], sum);
    }
  } else {
    // rare slow path: exact stable-rank scan (matches jnp.argsort tie order)
    int c_lt_lo = 0, c_lt_hi = 0;
#pragma unroll
    for (int d = 0; d < SZ; ++d) {
      float ko = ksf[d * F];
      c_lt_lo += (ko < lo) ? 1 : 0;
      c_lt_hi += (ko < hi) ? 1 : 0;
    }
    int run_lo = 0, run_hi = 0;
    const int nb = n - b;
#pragma unroll
    for (int d = 0; d < SZ; ++d) {
      const float kd = ksf[d * F];
      const float m = kd * nrm[d];  // pads: FLT_MAX*0 = 0
      const bool eql = (kd == lo);
      const bool eqh = (kd == hi);
      const bool lh = (lo < hi);
      const bool btw = (kd > lo) & (kd < hi);
      const int r_lo = c_lt_lo + run_lo;
      const int r_hi = c_lt_hi + run_hi;
      const bool inc = btw
                     | (eql & (r_lo >= b) & (lh | (r_lo < nb)))
                     | (lh & eqh & (r_hi < nb));
      sum += inc ? m : 0.f;
      run_lo += eql ? 1 : 0;
      run_hi += eqh ? 1 : 0;
    }
  }
  return sum;
}

__global__ __launch_bounds__(128) void gcn_stage1(const float* __restrict__ h,
                                                  const float* __restrict__ norm,
                                                  const int* __restrict__ nbr,
                                                  const int* __restrict__ deg,
                                                  float* __restrict__ accum) {
  __shared__ float ks[MAXD * F];  // 16 KB: [d][f], thread-private column f
  const int i = blockIdx.x;
  const int f = threadIdx.x;
  const int n = deg[i];           // block-uniform
  const float ni = norm[i];
  const float hif = h[i * F + f];
  const int idx = i * F + f;

  if (n <= 3) {  // N_NEIGH_THRESHOLD branch
    accum[idx] = (float)n * hif * ni * ni;
    return;
  }

  int b = n / 2 - (1 - (n & 1));
  int bcap = (int)floorf((float)n * 0.45f);
  b = b < bcap ? b : bcap;
  b = b > 1 ? b : 1;

  const int* nbr_row = nbr + i * MAXD;
  volatile float* ksf = ks + f;
  float ts;
  if (n <= 4)       ts = trimmed_sum<4>(h, norm, nbr_row, ksf, n, f, b);
  else if (n <= 8)  ts = trimmed_sum<8>(h, norm, nbr_row, ksf, n, f, b);
  else if (n <= 16) ts = trimmed_sum<16>(h, norm, nbr_row, ksf, n, f, b);
  else              ts = trimmed_sum<32>(h, norm, nbr_row, ksf, n, f, b);

  accum[idx] = (ts + hif * ni * (float)(2 * b)) * ni;
}

// ---------------- stage 2: out = relu(accum @ W + bias) ----------------
// 256 threads, 32 rows x 128 cols per block, k-chunk=32.
// Per k-step per thread: 1 ds_read_b128 (W, 512B distinct/wave) + 4 broadcast
// ds_read_b32 (A) vs 16 FMA -> VALU:LDS = 4:1 = the 4-SIMD/1-LDS-pipe balance.
// LDS 20.6 KB -> 7 blocks/CU (28 waves) for latency hiding.
__global__ __launch_bounds__(256) void gcn_gemm(const float* __restrict__ A,
                                                const float* __restrict__ W,
                                                const float* __restrict__ bias,
                                                float* __restrict__ out) {
  __shared__ float Ws[32 * F];   // 16 KB: k-chunk of W, [k][c]
  __shared__ float As[32 * 36];  // 4.6 KB: [row][k], pad 36 keeps 16B align
  const int t = threadIdx.x;
  const int tx = t & 31;         // col group: cols tx*4..tx*4+3
  const int ty = t >> 5;         // row group: rows ty*4..ty*4+3
  const int row0 = blockIdx.x * 32;
  const int ar = t >> 3, ak = t & 7;  // A staging coords

  float acc[4][4];
#pragma unroll
  for (int r = 0; r < 4; ++r)
#pragma unroll
    for (int c = 0; c < 4; ++c) acc[r][c] = 0.f;

#pragma unroll
  for (int kc = 0; kc < F; kc += 32) {
    __syncthreads();  // protect As/Ws from previous chunk's readers
    // stage A: 32 rows x 32 k (1 float4/thread, coalesced 128B/row-segment)
    float4 av = *(const float4*)(A + (row0 + ar) * F + kc + ak * 4);
    *(float4*)(As + ar * 36 + ak * 4) = av;
    // stage W: 32 k x 128 c = 1024 float4 (4/thread, fully coalesced)
#pragma unroll
    for (int u = 0; u < 4; ++u) {
      int idx2 = u * 256 + t;
      *(float4*)(Ws + idx2 * 4) = *(const float4*)(W + kc * F + idx2 * 4);
    }
    __syncthreads();
#pragma unroll 8
    for (int k = 0; k < 32; ++k) {
      float4 w4 = *(const float4*)(Ws + k * F + tx * 4);
      float a0 = As[(ty * 4 + 0) * 36 + k];
      float a1 = As[(ty * 4 + 1) * 36 + k];
      float a2 = As[(ty * 4 + 2) * 36 + k];
      float a3 = As[(ty * 4 + 3) * 36 + k];
      acc[0][0] = fmaf(a0, w4.x, acc[0][0]); acc[0][1] = fmaf(a0, w4.y, acc[0][1]);
      acc[0][2] = fmaf(a0, w4.z, acc[0][2]); acc[0][3] = fmaf(a0, w4.w, acc[0][3]);
      acc[1][0] = fmaf(a1, w4.x, acc[1][0]); acc[1][1] = fmaf(a1, w4.y, acc[1][1]);
      acc[1][2] = fmaf(a1, w4.z, acc[1][2]); acc[1][3] = fmaf(a1, w4.w, acc[1][3]);
      acc[2][0] = fmaf(a2, w4.x, acc[2][0]); acc[2][1] = fmaf(a2, w4.y, acc[2][1]);
      acc[2][2] = fmaf(a2, w4.z, acc[2][2]); acc[2][3] = fmaf(a2, w4.w, acc[2][3]);
      acc[3][0] = fmaf(a3, w4.x, acc[3][0]); acc[3][1] = fmaf(a3, w4.y, acc[3][1]);
      acc[3][2] = fmaf(a3, w4.z, acc[3][2]); acc[3][3] = fmaf(a3, w4.w, acc[3][3]);
    }
  }

  float4 bv = *(const float4*)(bias + tx * 4);
#pragma unroll
  for (int r = 0; r < 4; ++r) {
    float4 o;
    o.x = fmaxf(acc[r][0] + bv.x, 0.f);
    o.y = fmaxf(acc[r][1] + bv.y, 0.f);
    o.z = fmaxf(acc[r][2] + bv.z, 0.f);
    o.w = fmaxf(acc[r][3] + bv.w, 0.f);
    *(float4*)(out + (row0 + ty * 4 + r) * F + tx * 4) = o;
  }
}

extern "C" void kernel_launch(void* const* d_in, const int* in_sizes, int n_in,
                              void* d_out, int out_size, void* d_ws, size_t ws_size,
                              hipStream_t stream) {
  const float* h = (const float*)d_in[0];
  const float* norm = (const float*)d_in[1];
  const float* weight = (const float*)d_in[2];
  const float* bias = (const float*)d_in[3];
  const int* nbr = (const int*)d_in[4];
  const int* deg = (const int*)d_in[5];
  float* out = (float*)d_out;
  float* accum = (float*)d_ws;  // 20000*128*4 = 10.24 MB scratch

  gcn_stage1<<<N_NODES, 128, 0, stream>>>(h, norm, nbr, deg, accum);
  gcn_gemm<<<N_NODES / 32, 256, 0, stream>>>(accum, weight, bias, out);
}

// Round 4
// 140.983 us; speedup vs baseline: 1.4888x; 1.4888x over previous
//
#include <hip/hip_runtime.h>
#include <cfloat>
#include <cmath>

#define N_NODES 20000
#define MAXD 32
#define F 128

// ---------------- trimmed-mean aggregation (register version, round-2 best) --

// Batcher odd-even mergesort network, ascending, fully unrolled.
// CE counts: SZ=4:5, 8:19, 16:63, 32:191.
template <int SZ>
__device__ __forceinline__ void oe_sort(float (&a)[SZ]) {
#pragma unroll
  for (int p = 1; p < SZ; p <<= 1) {
#pragma unroll
    for (int q = p; q >= 1; q >>= 1) {
#pragma unroll
      for (int j = q % p; j <= SZ - 1 - q; j += 2 * q) {
#pragma unroll
        for (int i = 0; i < q; ++i) {
          int x = i + j, y = i + j + q;
          if (y < SZ && (x / (2 * p)) == (y / (2 * p))) {
            float mn = fminf(a[x], a[y]);
            float mx = fmaxf(a[x], a[y]);
            a[x] = mn;
            a[y] = mx;
          }
        }
      }
    }
  }
}

// extract element at (wave-uniform) position p from a statically-indexed register array
template <int SZ>
__device__ __forceinline__ float extract_pos(const float (&k)[SZ], int p) {
  float sel[SZ];
#pragma unroll
  for (int i = 0; i < SZ; ++i) sel[i] = k[i];
#pragma unroll
  for (int w = SZ >> 1; w >= 1; w >>= 1) {
    bool take = (p & w) != 0;
#pragma unroll
    for (int i = 0; i < w; ++i) sel[i] = take ? sel[i + w] : sel[i];
  }
  return sel[0];
}

// Exact trimmed sum: payloads (key*norm_src) whose STABLE rank (key asc, ties
// by slot — matches jnp.argsort) lies in [b, n-b).
// Fast path: when sorted[b-1] < sorted[b] and sorted[n-b-1] < sorted[n-b],
// rank-membership == value-membership in [lo, hi] (exact, incl. lo==hi runs).
// Slow path (rare boundary ties): exact stable-rank scan.
template <int SZ>
__device__ __forceinline__ float trimmed_sum(const float* __restrict__ h,
                                             const float* __restrict__ norm,
                                             const int* __restrict__ nbr_row,
                                             int n, int f, int b) {
  float ko[SZ];
  float nrm[SZ];  // wave-uniform -> SGPRs
#pragma unroll
  for (int d = 0; d < SZ; ++d) {
    if (d < n) {  // uniform branch (n wave-uniform)
      int src = nbr_row[d];       // scalar load
      nrm[d] = norm[src];         // scalar load
      ko[d] = h[src * F + f];     // vector load, coalesced
    } else {
      nrm[d] = 0.f;
      ko[d] = FLT_MAX;            // pads sort past all valid keys
    }
  }

  float k[SZ];
#pragma unroll
  for (int d = 0; d < SZ; ++d) k[d] = ko[d];
  oe_sort<SZ>(k);

  const float lo  = extract_pos<SZ>(k, b);          // rank b (kept)
  const float hi  = extract_pos<SZ>(k, n - b - 1);  // rank n-b-1 (kept)
  const float lom = extract_pos<SZ>(k, b - 1);      // rank b-1 (trimmed)
  const float him = extract_pos<SZ>(k, n - b);      // rank n-b (trimmed)

  float sum = 0.f;
  if ((lom < lo) & (hi < him)) {
#pragma unroll
    for (int d = 0; d < SZ; ++d) {
      bool keep = (ko[d] >= lo) & (ko[d] <= hi);  // pads (FLT_MAX) fail
      sum = fmaf(keep ? ko[d] : 0.f, nrm[d], sum);
    }
  } else {
    int c_lt_lo = 0, c_lt_hi = 0;
#pragma unroll
    for (int d = 0; d < SZ; ++d) {
      c_lt_lo += (ko[d] < lo) ? 1 : 0;
      c_lt_hi += (ko[d] < hi) ? 1 : 0;
    }
    int run_lo = 0, run_hi = 0;
    const int nb = n - b;
#pragma unroll
    for (int d = 0; d < SZ; ++d) {
      const float kd = ko[d];
      const float m = kd * nrm[d];  // pads: FLT_MAX*0 = 0
      const bool eql = (kd == lo);
      const bool eqh = (kd == hi);
      const bool lh = (lo < hi);
      const bool btw = (kd > lo) & (kd < hi);
      const int r_lo = c_lt_lo + run_lo;  // stable rank if kd==lo
      const int r_hi = c_lt_hi + run_hi;  // stable rank if kd==hi
      const bool inc = btw
                     | (eql & (r_lo >= b) & (lh | (r_lo < nb)))
                     | (lh & eqh & (r_hi < nb));
      sum += inc ? m : 0.f;
      run_lo += eql ? 1 : 0;
      run_hi += eqh ? 1 : 0;
    }
  }
  return sum;
}

// ---------------- fused kernel: aggregate + matvec + bias + relu -------------
// Block i owns node i: 128 threads = 1 thread per feature.
// Phase 1: trimmed aggregation -> accum row in LDS (512 B).
// Phase 2: out[i,:] = relu(accum_row @ W + bias): thread f -> (f-chunk g = f>>5,
//          col-quad c4 = f&31); float4 W loads (two 512B segments/wave-instr,
//          W is 64KB -> L1/L2-hot); partials reduced through 2KB LDS.
__global__ __launch_bounds__(128, 4) void gcn_fused(const float* __restrict__ h,
                                                    const float* __restrict__ norm,
                                                    const int* __restrict__ nbr,
                                                    const int* __restrict__ deg,
                                                    const float* __restrict__ W,
                                                    const float* __restrict__ bias,
                                                    float* __restrict__ out) {
  __shared__ float as_row[F];     // accum row
  __shared__ float4 ps[4][32];    // partial sums [f-chunk][col-quad]
  const int i = blockIdx.x;
  const int f = threadIdx.x;
  const int n = deg[i];           // block-uniform
  const float ni = norm[i];
  const float hif = h[i * F + f];

  float v;
  if (n <= 3) {  // N_NEIGH_THRESHOLD branch (no early return: barriers below)
    v = (float)n * hif * ni * ni;
  } else {
    int b = n / 2 - (1 - (n & 1));
    int bcap = (int)floorf((float)n * 0.45f);
    b = b < bcap ? b : bcap;
    b = b > 1 ? b : 1;

    const int* nbr_row = nbr + i * MAXD;
    float ts;
    if (n <= 4)       ts = trimmed_sum<4>(h, norm, nbr_row, n, f, b);
    else if (n <= 8)  ts = trimmed_sum<8>(h, norm, nbr_row, n, f, b);
    else if (n <= 16) ts = trimmed_sum<16>(h, norm, nbr_row, n, f, b);
    else              ts = trimmed_sum<32>(h, norm, nbr_row, n, f, b);

    v = (ts + hif * ni * (float)(2 * b)) * ni;
  }
  as_row[f] = v;
  __syncthreads();

  // matvec: p[c4] = sum_{fk in chunk g} as_row[fk] * W[fk, 4c4..4c4+3]
  const int g = f >> 5, c4 = f & 31;
  const float4* __restrict__ W4 = (const float4*)W;
  float4 p = make_float4(0.f, 0.f, 0.f, 0.f);
#pragma unroll
  for (int j = 0; j < 32; ++j) {
    const int fk = g * 32 + j;
    const float a = as_row[fk];            // 2 addrs/wave -> free broadcast
    const float4 w = W4[fk * 32 + c4];     // 512B contiguous per half-wave
    p.x = fmaf(a, w.x, p.x);
    p.y = fmaf(a, w.y, p.y);
    p.z = fmaf(a, w.z, p.z);
    p.w = fmaf(a, w.w, p.w);
  }
  ps[g][c4] = p;
  __syncthreads();

  if (f < 32) {
    const float4 q0 = ps[0][f], q1 = ps[1][f], q2 = ps[2][f], q3 = ps[3][f];
    const float4 bv = ((const float4*)bias)[f];
    float4 o;
    o.x = fmaxf(q0.x + q1.x + q2.x + q3.x + bv.x, 0.f);
    o.y = fmaxf(q0.y + q1.y + q2.y + q3.y + bv.y, 0.f);
    o.z = fmaxf(q0.z + q1.z + q2.z + q3.z + bv.z, 0.f);
    o.w = fmaxf(q0.w + q1.w + q2.w + q3.w + bv.w, 0.f);
    ((float4*)out)[i * 32 + f] = o;        // 512B coalesced
  }
}

extern "C" void kernel_launch(void* const* d_in, const int* in_sizes, int n_in,
                              void* d_out, int out_size, void* d_ws, size_t ws_size,
                              hipStream_t stream) {
  const float* h = (const float*)d_in[0];
  const float* norm = (const float*)d_in[1];
  const float* weight = (const float*)d_in[2];
  const float* bias = (const float*)d_in[3];
  const int* nbr = (const int*)d_in[4];
  const int* deg = (const int*)d_in[5];
  float* out = (float*)d_out;

  gcn_fused<<<N_NODES, 128, 0, stream>>>(h, norm, nbr, deg, weight, bias, out);
}